// Round 5
// baseline (616.263 us; speedup 1.0000x reference)
//
#include <hip/hip_runtime.h>

// N=32, C=192, T=256, V=25, S=3, mid=64
#define TV 6400
#define NCH 192
#define D3 576

typedef unsigned short u16;
typedef unsigned int   u32;

typedef __attribute__((ext_vector_type(8))) short bf16x8;
typedef __attribute__((ext_vector_type(4))) float f32x4;

__device__ __forceinline__ float bf2f(u32 h) { return __uint_as_float(h << 16); }
__device__ __forceinline__ u16 f2bf(float f) {
    u32 u = __float_as_uint(f);
    return (u16)((u + 0x7FFFu + ((u >> 16) & 1u)) >> 16);
}

// ---------------------------------------------------------------------------
// Kernel 0a: cast weights fp32 -> bf16.
// w_in is emitted in MFMA-FRAGMENT-LINEAR order: fragment
//   f = (((dt*2+wd)*2+mt)*3+kk)*2+ks   (216 fragments, 1 KB each)
// holds, at byte offset lane*16, the 8 bf16 A-operand elements
//   w_in[dt*64+wd*32+mt*16+(lane&15)][(kk*8+ks*4+(lane>>4))*8 + 0..7]
// so k_qkv reads each A-fragment with ONE coalesced global_load_dwordx4.
// w_ff (appended after 55296 u32) stays flat.
// ---------------------------------------------------------------------------
__global__ __launch_bounds__(256) void k_wcast(const float* __restrict__ w_in,
                                               const float* __restrict__ w_ff,
                                               u32* __restrict__ wb) {
    int i = blockIdx.x * 256 + threadIdx.x;   // < 73728
    float2 f;
    if (i < 55296) {
        int frag = i >> 8, r = i & 255;
        int lane = r >> 2, ep = r & 3;
        int ks = frag & 1;
        int t1 = frag >> 1;          // (dt*4+wd*2+mt)*3 + kk
        int kk = t1 % 3;
        int t2 = t1 / 3;             // dt*4 + wd*2 + mt
        int mt = t2 & 1, wd = (t2 >> 1) & 1, dt = t2 >> 2;
        int d = dt * 64 + wd * 32 + mt * 16 + (lane & 15);
        int c = (kk * 8 + ks * 4 + (lane >> 4)) * 8 + ep * 2;
        f = *(const float2*)(w_in + d * 192 + c);
    } else {
        f = *(const float2*)(w_ff + 2 * (i - 55296));
    }
    wb[i] = (u32)f2bf(f.x) | ((u32)f2bf(f.y) << 16);
}

// ---------------------------------------------------------------------------
// Kernel 1: fused x-transpose + QKV projection via MFMA.
// A = w fragments loaded DIRECTLY from global (fragment-linear, L2-resident,
//     one coalesced dwordx4 per fragment) -- no As LDS, no staging barriers.
// B = x tile [128p][192c] bf16 in LDS, built by transposed scalar reads of x
//     (each load = 2x128B coalesced segments).  Bs is read-only after build:
//     the dt loop contains ZERO __syncthreads.
// LDS = 48 KB -> 3 blocks/CU, 12 waves/CU, waves fully decoupled.
// C frag: row(kq*4+r)=d, col(ml)=p.
// Q,K (dt 0..5): stored transposed to qt/kt [b][p][c64] (k-order v*64+c).
// V (dt 6..8): stored to qkv [n][d][p] for k_trv.
// ---------------------------------------------------------------------------
__global__ __launch_bounds__(256) void k_qkv(const float* __restrict__ x,
                                             const u16* __restrict__ w_frag,
                                             const float* __restrict__ b_in,
                                             u16* __restrict__ qkv,
                                             u16* __restrict__ qt,
                                             u16* __restrict__ kt) {
    const int p0 = blockIdx.x * 128, n = blockIdx.y;
    const int tid = threadIdx.x;
    const int wid = tid >> 6, lane = tid & 63;
    const int wm = wid & 1, wn = wid >> 1;      // d-half, p-half
    const int ml = lane & 15, kq = lane >> 4;

    __shared__ __align__(16) char Bs[128 * 384];  // x tile [p][192c] bf16, swizzled

    // ---- Build Bs: transposed read of x (each thread: one p, 96 c) ----
    {
        const int p = tid >> 1, ch = tid & 1;
        const float* xp = x + (size_t)n * NCH * TV + p0 + p;
#pragma unroll
        for (int j = 0; j < 12; ++j) {
            int g = ch * 12 + j;                 // c = g*8 .. g*8+7
            u32 buf[4];
#pragma unroll
            for (int e = 0; e < 4; ++e) {
                float f0 = xp[(size_t)(g * 8 + 2 * e) * TV];
                float f1 = xp[(size_t)(g * 8 + 2 * e + 1) * TV];
                buf[e] = (u32)f2bf(f0) | ((u32)f2bf(f1) << 16);
            }
            uint4 u; u.x = buf[0]; u.y = buf[1]; u.z = buf[2]; u.w = buf[3];
            *(uint4*)(Bs + p * 384 + (((g & ~7) | ((g ^ p) & 7)) << 4)) = u;
        }
    }
    __syncthreads();   // the ONLY barrier in the kernel

    // ---- d-tile loop (barrier-free) ----
    for (int dt = 0; dt < 9; ++dt) {
        f32x4 acc[2][4];
#pragma unroll
        for (int i = 0; i < 2; i++)
#pragma unroll
            for (int j = 0; j < 4; j++)
#pragma unroll
                for (int r = 0; r < 4; r++) acc[i][j][r] = 0.f;

#pragma unroll
        for (int kk = 0; kk < 3; ++kk)
#pragma unroll
            for (int ks = 0; ks < 2; ++ks) {
                int g = kk * 8 + ks * 4 + kq;
                bf16x8 aw[2], bx[4];
#pragma unroll
                for (int mt = 0; mt < 2; ++mt) {
                    int frag = ((((dt * 2 + wm) * 2 + mt) * 3 + kk) * 2 + ks);
                    aw[mt] = *(const bf16x8*)(w_frag + (size_t)frag * 512 + lane * 8);
                }
#pragma unroll
                for (int nt = 0; nt < 4; ++nt) {
                    int row = wn * 64 + nt * 16 + ml;
                    bx[nt] = *(const bf16x8*)(Bs + row * 384 + (((g & ~7) | ((g ^ row) & 7)) << 4));
                }
#pragma unroll
                for (int mt = 0; mt < 2; ++mt)
#pragma unroll
                    for (int nt = 0; nt < 4; ++nt)
                        acc[mt][nt] = __builtin_amdgcn_mfma_f32_16x16x32_bf16(aw[mt], bx[nt], acc[mt][nt], 0, 0, 0);
            }

        if (dt < 6) {
            // Q/K: transposed store to qt/kt [b][p][c64], 8B contiguous per frag.
            const int s = (dt < 3) ? dt : dt - 3;
            u16* dstb = (dt < 3 ? qt : kt) + ((size_t)(n * 3 + s) * 6400 + p0) * 64;
#pragma unroll
            for (int mt = 0; mt < 2; ++mt) {
                int c = wm * 32 + mt * 16 + kq * 4;
                float4 bias = *(const float4*)(b_in + dt * 64 + c);
#pragma unroll
                for (int nt = 0; nt < 4; ++nt) {
                    int p = wn * 64 + nt * 16 + ml;
                    u32 w0 = (u32)f2bf(acc[mt][nt][0] + bias.x) | ((u32)f2bf(acc[mt][nt][1] + bias.y) << 16);
                    u32 w1 = (u32)f2bf(acc[mt][nt][2] + bias.z) | ((u32)f2bf(acc[mt][nt][3] + bias.w) << 16);
                    uint2 u; u.x = w0; u.y = w1;
                    *(uint2*)(dstb + (size_t)p * 64 + c) = u;
                }
            }
        } else {
            // V: [n][d][p] layout for k_trv.
#pragma unroll
            for (int mt = 0; mt < 2; ++mt) {
                int d = dt * 64 + wm * 32 + mt * 16 + kq * 4;
                float4 bias = *(const float4*)(b_in + d);
                u16* vdst = qkv + ((size_t)n * D3 + d) * TV;
#pragma unroll
                for (int nt = 0; nt < 4; ++nt) {
                    int p = p0 + wn * 64 + nt * 16 + ml;
                    vdst[(size_t)0 * TV + p] = f2bf(acc[mt][nt][0] + bias.x);
                    vdst[(size_t)1 * TV + p] = f2bf(acc[mt][nt][1] + bias.y);
                    vdst[(size_t)2 * TV + p] = f2bf(acc[mt][nt][2] + bias.z);
                    vdst[(size_t)3 * TV + p] = f2bf(acc[mt][nt][3] + bias.w);
                }
            }
        }
    }
}

// ---------------------------------------------------------------------------
// Kernel 3: scores MFMA. att[b][t][q] = tanh(sum_k qt[b][t][k]*kt[b][q][k]/1600)
// (k-ordering is v*64+c; identical for qt and kt, so the sum is unchanged.)
// ---------------------------------------------------------------------------
__global__ __launch_bounds__(256) void k_scores(const u16* __restrict__ qt,
                                                const u16* __restrict__ kt,
                                                u16* __restrict__ att) {
    const int b = blockIdx.z, t0 = blockIdx.y * 128, q0 = blockIdx.x * 64;
    const int tid = threadIdx.x;
    const int wid = tid >> 6, lane = tid & 63;
    const int wm = wid & 1, wn = wid >> 1;
    const int ml = lane & 15, kq = lane >> 4;

    __shared__ __align__(16) char As[128 * 128];
    __shared__ __align__(16) char Bs[64 * 128];

    f32x4 acc[4][2];
#pragma unroll
    for (int i = 0; i < 4; i++)
#pragma unroll
        for (int j = 0; j < 2; j++)
#pragma unroll
            for (int r = 0; r < 4; r++) acc[i][j][r] = 0.f;

    const u16* qb = qt + (size_t)b * 256 * 1600;
    const u16* kb = kt + (size_t)b * 256 * 1600;

    for (int kc = 0; kc < 1600; kc += 64) {
#pragma unroll
        for (int r = 0; r < 4; r++) {
            int idx = tid + 256 * r;
            int row = idx >> 3, g = idx & 7;
            uint4 v = *(const uint4*)(qb + (size_t)(t0 + row) * 1600 + kc + g * 8);
            *(uint4*)(As + row * 128 + (((g ^ row) & 7) << 4)) = v;
        }
#pragma unroll
        for (int r = 0; r < 2; r++) {
            int idx = tid + 256 * r;
            int row = idx >> 3, g = idx & 7;
            uint4 v = *(const uint4*)(kb + (size_t)(q0 + row) * 1600 + kc + g * 8);
            *(uint4*)(Bs + row * 128 + (((g ^ row) & 7) << 4)) = v;
        }
        __syncthreads();
#pragma unroll
        for (int ks = 0; ks < 2; ks++) {
            int gb = ks * 4 + kq;
            bf16x8 a[4], bb[2];
#pragma unroll
            for (int mt = 0; mt < 4; mt++) {
                int row = wm * 64 + mt * 16 + ml;
                a[mt] = *(const bf16x8*)(As + row * 128 + (((gb ^ row) & 7) << 4));
            }
#pragma unroll
            for (int nt = 0; nt < 2; nt++) {
                int row = wn * 32 + nt * 16 + ml;
                bb[nt] = *(const bf16x8*)(Bs + row * 128 + (((gb ^ row) & 7) << 4));
            }
#pragma unroll
            for (int mt = 0; mt < 4; mt++)
#pragma unroll
                for (int nt = 0; nt < 2; nt++)
                    acc[mt][nt] = __builtin_amdgcn_mfma_f32_16x16x32_bf16(a[mt], bb[nt], acc[mt][nt], 0, 0, 0);
        }
        __syncthreads();
    }

    const float sc = 1.0f / 1600.0f;
    u16* ab = att + (size_t)b * 65536;
#pragma unroll
    for (int mt = 0; mt < 4; mt++)
#pragma unroll
        for (int nt = 0; nt < 2; nt++) {
            int q = q0 + wn * 32 + nt * 16 + ml;
#pragma unroll
            for (int r = 0; r < 4; r++) {
                int t = t0 + wm * 64 + mt * 16 + kq * 4 + r;
                ab[(size_t)t * 256 + q] = f2bf(tanhf(acc[mt][nt][r] * sc));
            }
        }
}

// ---------------------------------------------------------------------------
// Kernel 3b: transpose V part of qkv -> vt [b][v*64+c][q], q contiguous.
// ---------------------------------------------------------------------------
__global__ __launch_bounds__(256) void k_trv(const u16* __restrict__ qkv,
                                             u16* __restrict__ vt) {
    const int q0 = blockIdx.x * 32;
    const int c0 = blockIdx.y * 32;
    const int b  = blockIdx.z;
    const int n = b / 3, s = b % 3;
    const int tid = threadIdx.x;

    __shared__ u16 L[32 * 800];   // [c][q*25+v] for 32 q, 50 KB

    const u16* src = qkv + ((size_t)n * D3 + 384 + s * 64 + c0) * TV + q0 * 25;
#pragma unroll
    for (int r = 0; r < 13; ++r) {
        int idx = tid + 256 * r;
        if (idx < 3200) {
            int c = idx / 100, w = idx - 100 * c;
            uint4 v = *(const uint4*)(src + (size_t)c * TV + w * 8);
            *(uint4*)&L[c * 800 + w * 8] = v;
        }
    }
    __syncthreads();

    u16* dst = vt + ((size_t)b * 1600 + c0) * 256 + q0;
#pragma unroll
    for (int r = 0; r < 4; ++r) {
        int idx = tid + 256 * r;
        if (idx < 800) {
            int c = idx / 25, v = idx - 25 * c;
            const u16* lp = &L[c * 800 + v];
            u32 buf[16];
#pragma unroll
            for (int j = 0; j < 16; ++j) {
                u32 lo = lp[(2 * j) * 25];
                u32 hi = lp[(2 * j + 1) * 25];
                buf[j] = lo | (hi << 16);
            }
            u16* dp = dst + (size_t)(v * 64 + c) * 256;
#pragma unroll
            for (int q4 = 0; q4 < 4; ++q4) {
                uint4 u; u.x = buf[q4 * 4]; u.y = buf[q4 * 4 + 1];
                u.z = buf[q4 * 4 + 2]; u.w = buf[q4 * 4 + 3];
                *(uint4*)(dp + q4 * 8) = u;
            }
        }
    }
}

// ---------------------------------------------------------------------------
// Kernel 4: AV MFMA.
// y[b][t][cv=v*64+c] = sum_q att[b][t][q] * vt[b][cv][q]
// ---------------------------------------------------------------------------
__global__ __launch_bounds__(256) void k_av(const u16* __restrict__ att,
                                            const u16* __restrict__ vt,
                                            u16* __restrict__ y_t) {
    const int b = blockIdx.z, t0 = blockIdx.y * 128, v = blockIdx.x;
    const int n = b / 3, s = b % 3;
    const int tid = threadIdx.x;
    const int wid = tid >> 6, lane = tid & 63;
    const int wm = wid & 1, wn = wid >> 1;
    const int ml = lane & 15, kq = lane >> 4;

    __shared__ __align__(16) char As[128 * 128];
    __shared__ __align__(16) char Bs[64 * 128];

    f32x4 acc[4][2];
#pragma unroll
    for (int i = 0; i < 4; i++)
#pragma unroll
        for (int j = 0; j < 2; j++)
#pragma unroll
            for (int r = 0; r < 4; r++) acc[i][j][r] = 0.f;

    const u16* ab = att + (size_t)b * 65536;                     // [t][q]
    const u16* vb = vt + ((size_t)b * 1600 + v * 64) * 256;      // [c][q]

    for (int kc = 0; kc < 256; kc += 64) {
#pragma unroll
        for (int r = 0; r < 4; r++) {
            int idx = tid + 256 * r;
            int row = idx >> 3, g = idx & 7;
            uint4 u = *(const uint4*)(ab + (size_t)(t0 + row) * 256 + kc + g * 8);
            *(uint4*)(As + row * 128 + (((g ^ row) & 7) << 4)) = u;
        }
#pragma unroll
        for (int r = 0; r < 2; r++) {
            int idx = tid + 256 * r;
            int row = idx >> 3, g = idx & 7;
            uint4 u = *(const uint4*)(vb + (size_t)row * 256 + kc + g * 8);
            *(uint4*)(Bs + row * 128 + (((g ^ row) & 7) << 4)) = u;
        }
        __syncthreads();
#pragma unroll
        for (int ks = 0; ks < 2; ks++) {
            int gb = ks * 4 + kq;
            bf16x8 a[4], bb[2];
#pragma unroll
            for (int mt = 0; mt < 4; mt++) {
                int row = wm * 64 + mt * 16 + ml;
                a[mt] = *(const bf16x8*)(As + row * 128 + (((gb ^ row) & 7) << 4));
            }
#pragma unroll
            for (int nt = 0; nt < 2; nt++) {
                int row = wn * 32 + nt * 16 + ml;
                bb[nt] = *(const bf16x8*)(Bs + row * 128 + (((gb ^ row) & 7) << 4));
            }
#pragma unroll
            for (int mt = 0; mt < 4; mt++)
#pragma unroll
                for (int nt = 0; nt < 2; nt++)
                    acc[mt][nt] = __builtin_amdgcn_mfma_f32_16x16x32_bf16(a[mt], bb[nt], acc[mt][nt], 0, 0, 0);
        }
        __syncthreads();
    }

#pragma unroll
    for (int mt = 0; mt < 4; mt++)
#pragma unroll
        for (int nt = 0; nt < 2; nt++) {
            int cg = s * 64 + wn * 32 + nt * 16 + ml;
#pragma unroll
            for (int r = 0; r < 4; r++) {
                int t = t0 + wm * 64 + mt * 16 + kq * 4 + r;
                y_t[((size_t)n * TV + t * 25 + v) * 192 + cg] = f2bf(acc[mt][nt][r]);
            }
        }
}

// ---------------------------------------------------------------------------
// Kernel 5: FF MFMA + BN + residual + LeakyReLU.
// ---------------------------------------------------------------------------
__global__ __launch_bounds__(256) void k_ff(const u16* __restrict__ y_t,
                                            const float* __restrict__ x,
                                            const u16* __restrict__ w_ffb,
                                            const float* __restrict__ b_ff,
                                            const float* __restrict__ gamma,
                                            const float* __restrict__ beta,
                                            const float* __restrict__ mean,
                                            const float* __restrict__ var,
                                            float* __restrict__ out) {
    const int n = blockIdx.z, d0 = blockIdx.y * 64, p0 = blockIdx.x * 128;
    const int tid = threadIdx.x;
    const int wid = tid >> 6, lane = tid & 63;
    const int wn = wid;
    const int ml = lane & 15, kq = lane >> 4;

    __shared__ __align__(16) char Aw[64 * 128];
    __shared__ __align__(16) char By[128 * 128];

    f32x4 acc[4][2];
#pragma unroll
    for (int i = 0; i < 4; i++)
#pragma unroll
        for (int j = 0; j < 2; j++)
#pragma unroll
            for (int r = 0; r < 4; r++) acc[i][j][r] = 0.f;

    for (int kc = 0; kc < 192; kc += 64) {
#pragma unroll
        for (int r = 0; r < 2; r++) {
            int idx = tid + 256 * r;
            int row = idx >> 3, g = idx & 7;
            uint4 v = *(const uint4*)(w_ffb + (size_t)(d0 + row) * 192 + kc + g * 8);
            *(uint4*)(Aw + row * 128 + (((g ^ row) & 7) << 4)) = v;
        }
#pragma unroll
        for (int r = 0; r < 4; r++) {
            int idx = tid + 256 * r;
            int row = idx >> 3, g = idx & 7;
            uint4 v = *(const uint4*)(y_t + ((size_t)n * TV + p0 + row) * 192 + kc + g * 8);
            *(uint4*)(By + row * 128 + (((g ^ row) & 7) << 4)) = v;
        }
        __syncthreads();
#pragma unroll
        for (int ks = 0; ks < 2; ks++) {
            int gb = ks * 4 + kq;
            bf16x8 a[4], bb[2];
#pragma unroll
            for (int mt = 0; mt < 4; mt++) {
                int row = mt * 16 + ml;
                a[mt] = *(const bf16x8*)(Aw + row * 128 + (((gb ^ row) & 7) << 4));
            }
#pragma unroll
            for (int nt = 0; nt < 2; nt++) {
                int row = wn * 32 + nt * 16 + ml;
                bb[nt] = *(const bf16x8*)(By + row * 128 + (((gb ^ row) & 7) << 4));
            }
#pragma unroll
            for (int mt = 0; mt < 4; mt++)
#pragma unroll
                for (int nt = 0; nt < 2; nt++)
                    acc[mt][nt] = __builtin_amdgcn_mfma_f32_16x16x32_bf16(a[mt], bb[nt], acc[mt][nt], 0, 0, 0);
        }
        __syncthreads();
    }

#pragma unroll
    for (int mt = 0; mt < 4; mt++)
#pragma unroll
        for (int r = 0; r < 4; r++) {
            int d = d0 + mt * 16 + kq * 4 + r;
            float inv = gamma[d] * rsqrtf(var[d] + 1e-5f);
            float bias = b_ff[d], mu = mean[d], bt = beta[d];
#pragma unroll
            for (int nt = 0; nt < 2; nt++) {
                int p = p0 + wn * 32 + nt * 16 + ml;
                size_t xi = ((size_t)n * NCH + d) * TV + p;
                float v = acc[mt][nt][r] + bias;
                v = (v - mu) * inv + bt;
                float z = x[xi] + v;
                out[xi] = (z >= 0.f) ? z : 0.1f * z;
            }
        }
}

// ---------------------------------------------------------------------------
extern "C" void kernel_launch(void* const* d_in, const int* in_sizes, int n_in,
                              void* d_out, int out_size, void* d_ws, size_t ws_size,
                              hipStream_t stream) {
    const float* x     = (const float*)d_in[0];
    const float* w_in  = (const float*)d_in[1];
    const float* b_in  = (const float*)d_in[2];
    const float* w_ff  = (const float*)d_in[3];
    const float* b_ff  = (const float*)d_in[4];
    const float* gamma = (const float*)d_in[5];
    const float* beta  = (const float*)d_in[6];
    const float* mean  = (const float*)d_in[7];
    const float* var   = (const float*)d_in[8];

    // ws: qkv bf16 (only V region d in [384,576) used) [0,235929600) |
    // att bf16 [..,248512512) | y_t bf16 [..,327155712) | w_bf [..,327450624)
    u16* qkv = (u16*)d_ws;
    u16* att = (u16*)((char*)d_ws + 235929600ull);
    u16* y_t = (u16*)((char*)d_ws + 248512512ull);
    u32* wb  = (u32*)((char*)d_ws + 327155712ull);
    u16* w_frag = (u16*)wb;            // w_in, fragment-linear, 216 KiB
    u16* w_ffb  = w_frag + 110592;
    // d_out scratch: qt/kt written directly by k_qkv (transposed layout);
    // after k_scores consumes them, vt aliases qt; k_ff overwrites all last.
    u16* qt = (u16*)d_out;
    u16* kt = qt + 39321600ull;
    u16* vt = qt;
    float* out = (float*)d_out;

    k_wcast <<<dim3(288),        dim3(256), 0, stream>>>(w_in, w_ff, wb);
    k_qkv   <<<dim3(50, 32),     dim3(256), 0, stream>>>(x, w_frag, b_in, qkv, qt, kt);
    k_scores<<<dim3(4, 2, 96),   dim3(256), 0, stream>>>(qt, kt, att);
    k_trv   <<<dim3(8, 2, 96),   dim3(256), 0, stream>>>(qkv, vt);
    k_av    <<<dim3(25, 2, 96),  dim3(256), 0, stream>>>(att, vt, y_t);
    k_ff    <<<dim3(50, 3, 32),  dim3(256), 0, stream>>>(y_t, x, w_ffb, b_ff, gamma, beta, mean, var, out);
}

// Round 6
// 584.780 us; speedup vs baseline: 1.0538x; 1.0538x over previous
//
#include <hip/hip_runtime.h>

// N=32, C=192, T=256, V=25, S=3, mid=64
#define TV 6400
#define NCH 192
#define D3 576

typedef unsigned short u16;
typedef unsigned int   u32;

typedef __attribute__((ext_vector_type(8))) short bf16x8;
typedef __attribute__((ext_vector_type(4))) float f32x4;

__device__ __forceinline__ float bf2f(u32 h) { return __uint_as_float(h << 16); }
__device__ __forceinline__ u16 f2bf(float f) {
    u32 u = __float_as_uint(f);
    return (u16)((u + 0x7FFFu + ((u >> 16) & 1u)) >> 16);
}

// ---------------------------------------------------------------------------
// Kernel 0a: cast w_in (576x192) and w_ff (192x192) fp32 -> bf16, packed flat.
// ---------------------------------------------------------------------------
__global__ __launch_bounds__(256) void k_wcast(const float* __restrict__ w_in,
                                               const float* __restrict__ w_ff,
                                               u32* __restrict__ wb) {
    int i = blockIdx.x * 256 + threadIdx.x;   // < 73728
    float2 f;
    if (i < 55296) f = *(const float2*)(w_in + 2 * i);
    else           f = *(const float2*)(w_ff + 2 * (i - 55296));
    wb[i] = (u32)f2bf(f.x) | ((u32)f2bf(f.y) << 16);
}

// ---------------------------------------------------------------------------
// Kernel 1: fused x-transpose + QKV projection via MFMA (round-4 structure).
// Reads x [n][c][p] fp32 directly; builds Bs [64p][192c] bf16 in LDS via a
// fp32 scratch (aliases the As region, which is only live later).
// MFMA: A = w rows (d), B = x rows (p).  C frag: row(kq*4+r)=d, col(ml)=p.
// Q,K (dt 0..5): stored transposed to qt/kt [b][p][c64] (k-order v*64+c).
// V (dt 6..8): stored to qkv [n][d][p] for k_trv.
// LDS = 48 KB -> 3 blocks/CU.
// ---------------------------------------------------------------------------
__global__ __launch_bounds__(256) void k_qkv(const float* __restrict__ x,
                                             const u16* __restrict__ w_inb,
                                             const float* __restrict__ b_in,
                                             u16* __restrict__ qkv,
                                             u16* __restrict__ qt,
                                             u16* __restrict__ kt) {
    const int p0 = blockIdx.x * 64, n = blockIdx.y;
    const int tid = threadIdx.x;
    const int wid = tid >> 6, lane = tid & 63;
    const int wd = wid & 1, wp = wid >> 1;      // d-half, p-half
    const int ml = lane & 15, kq = lane >> 4;

    __shared__ __align__(16) char Bs[64 * 384]; // x tile [p][192c] bf16, swizzled
    __shared__ __align__(16) char As[64 * 384]; // w tile [d][192c] bf16, swizzled
    float* L = (float*)As;                      // [64][65] fp32 scratch, aliases As

    // ---- Build Bs from x (fused transpose+cast), 3 c-chunks of 64 ----
    for (int cc = 0; cc < 3; ++cc) {
        const float* xn = x + ((size_t)n * NCH + cc * 64) * TV + p0;
#pragma unroll
        for (int r = 0; r < 4; ++r) {
            int idx = tid + 256 * r;            // < 1024
            int c = idx >> 4, p4 = idx & 15;
            float4 v = *(const float4*)(xn + (size_t)c * TV + p4 * 4);
            *(float4*)&L[c * 65 + p4 * 4] = v;
        }
        __syncthreads();
        {
            int p = tid >> 2, cq = tid & 3;     // p in [0,64), c-quarter of 16
            u32 buf[8];
#pragma unroll
            for (int j = 0; j < 8; ++j) {
                float f0 = L[(cq * 16 + 2 * j) * 65 + p];
                float f1 = L[(cq * 16 + 2 * j + 1) * 65 + p];
                buf[j] = (u32)f2bf(f0) | ((u32)f2bf(f1) << 16);
            }
#pragma unroll
            for (int h = 0; h < 2; ++h) {
                int g = cc * 8 + cq * 2 + h;    // c = g*8 .. g*8+8
                uint4 u;
                u.x = buf[h * 4]; u.y = buf[h * 4 + 1];
                u.z = buf[h * 4 + 2]; u.w = buf[h * 4 + 3];
                *(uint4*)(Bs + p * 384 + (((g & ~7) | ((g ^ p) & 7)) << 4)) = u;
            }
        }
        __syncthreads();
    }

    // ---- d-tile loop ----
    for (int dt = 0; dt < 9; ++dt) {
        // Stage As: w rows dt*64 .. +64, all 192 c (1536 uint4)
#pragma unroll
        for (int r = 0; r < 6; ++r) {
            int idx = tid + 256 * r;
            int row = idx / 24, g = idx - row * 24;
            uint4 v = *(const uint4*)(w_inb + (size_t)(dt * 64 + row) * 192 + g * 8);
            *(uint4*)(As + row * 384 + (((g & ~7) | ((g ^ row) & 7)) << 4)) = v;
        }
        __syncthreads();

        f32x4 acc[2][2];
#pragma unroll
        for (int i = 0; i < 2; i++)
#pragma unroll
            for (int j = 0; j < 2; j++)
#pragma unroll
                for (int r = 0; r < 4; r++) acc[i][j][r] = 0.f;

#pragma unroll
        for (int kk = 0; kk < 3; ++kk)
#pragma unroll
            for (int ks = 0; ks < 2; ++ks) {
                int g = kk * 8 + ks * 4 + kq;
                bf16x8 aw[2], bx[2];
#pragma unroll
                for (int mt = 0; mt < 2; ++mt) {
                    int row = wd * 32 + mt * 16 + ml;
                    aw[mt] = *(const bf16x8*)(As + row * 384 + (((g & ~7) | ((g ^ row) & 7)) << 4));
                }
#pragma unroll
                for (int nt = 0; nt < 2; ++nt) {
                    int row = wp * 32 + nt * 16 + ml;
                    bx[nt] = *(const bf16x8*)(Bs + row * 384 + (((g & ~7) | ((g ^ row) & 7)) << 4));
                }
#pragma unroll
                for (int mt = 0; mt < 2; ++mt)
#pragma unroll
                    for (int nt = 0; nt < 2; ++nt)
                        acc[mt][nt] = __builtin_amdgcn_mfma_f32_16x16x32_bf16(aw[mt], bx[nt], acc[mt][nt], 0, 0, 0);
            }

        if (dt < 6) {
            const int s = (dt < 3) ? dt : dt - 3;
            u16* dstb = (dt < 3 ? qt : kt) + ((size_t)(n * 3 + s) * 6400 + p0) * 64;
#pragma unroll
            for (int mt = 0; mt < 2; ++mt) {
                int c = wd * 32 + mt * 16 + kq * 4;
                float4 bias = *(const float4*)(b_in + dt * 64 + c);
#pragma unroll
                for (int nt = 0; nt < 2; ++nt) {
                    int p = wp * 32 + nt * 16 + ml;
                    u32 w0 = (u32)f2bf(acc[mt][nt][0] + bias.x) | ((u32)f2bf(acc[mt][nt][1] + bias.y) << 16);
                    u32 w1 = (u32)f2bf(acc[mt][nt][2] + bias.z) | ((u32)f2bf(acc[mt][nt][3] + bias.w) << 16);
                    uint2 u; u.x = w0; u.y = w1;
                    *(uint2*)(dstb + (size_t)p * 64 + c) = u;
                }
            }
        } else {
#pragma unroll
            for (int mt = 0; mt < 2; ++mt) {
                int d = dt * 64 + wd * 32 + mt * 16 + kq * 4;
                float4 bias = *(const float4*)(b_in + d);
                u16* vdst = qkv + ((size_t)n * D3 + d) * TV;
#pragma unroll
                for (int nt = 0; nt < 2; ++nt) {
                    int p = p0 + wp * 32 + nt * 16 + ml;
                    vdst[(size_t)0 * TV + p] = f2bf(acc[mt][nt][0] + bias.x);
                    vdst[(size_t)1 * TV + p] = f2bf(acc[mt][nt][1] + bias.y);
                    vdst[(size_t)2 * TV + p] = f2bf(acc[mt][nt][2] + bias.z);
                    vdst[(size_t)3 * TV + p] = f2bf(acc[mt][nt][3] + bias.w);
                }
            }
        }
        __syncthreads();
    }
}

// ---------------------------------------------------------------------------
// Kernel 3: scores MFMA, 128x128 tile. att[b][t][q] = tanh(<qt_t,kt_q>/1600)
// Halves qt/kt re-reads vs 128x64; 32 MFMA per wave per k-iter.
// Grid 384 blocks -> all co-resident, no tail.
// ---------------------------------------------------------------------------
__global__ __launch_bounds__(256) void k_scores(const u16* __restrict__ qt,
                                                const u16* __restrict__ kt,
                                                u16* __restrict__ att) {
    const int b = blockIdx.z, t0 = blockIdx.y * 128, q0 = blockIdx.x * 128;
    const int tid = threadIdx.x;
    const int wid = tid >> 6, lane = tid & 63;
    const int wm = wid & 1, wn = wid >> 1;      // t-half, q-half
    const int ml = lane & 15, kq = lane >> 4;

    __shared__ __align__(16) char As[128 * 128];
    __shared__ __align__(16) char Bs[128 * 128];

    f32x4 acc[4][4];
#pragma unroll
    for (int i = 0; i < 4; i++)
#pragma unroll
        for (int j = 0; j < 4; j++)
#pragma unroll
            for (int r = 0; r < 4; r++) acc[i][j][r] = 0.f;

    const u16* qb = qt + (size_t)b * 256 * 1600;
    const u16* kb = kt + (size_t)b * 256 * 1600;

    for (int kc = 0; kc < 1600; kc += 64) {
#pragma unroll
        for (int r = 0; r < 4; r++) {
            int idx = tid + 256 * r;
            int row = idx >> 3, g = idx & 7;
            uint4 v = *(const uint4*)(qb + (size_t)(t0 + row) * 1600 + kc + g * 8);
            *(uint4*)(As + row * 128 + (((g ^ row) & 7) << 4)) = v;
        }
#pragma unroll
        for (int r = 0; r < 4; r++) {
            int idx = tid + 256 * r;
            int row = idx >> 3, g = idx & 7;
            uint4 v = *(const uint4*)(kb + (size_t)(q0 + row) * 1600 + kc + g * 8);
            *(uint4*)(Bs + row * 128 + (((g ^ row) & 7) << 4)) = v;
        }
        __syncthreads();
#pragma unroll
        for (int ks = 0; ks < 2; ks++) {
            int gb = ks * 4 + kq;
            bf16x8 a[4], bb[4];
#pragma unroll
            for (int mt = 0; mt < 4; mt++) {
                int row = wm * 64 + mt * 16 + ml;
                a[mt] = *(const bf16x8*)(As + row * 128 + (((gb ^ row) & 7) << 4));
            }
#pragma unroll
            for (int nt = 0; nt < 4; nt++) {
                int row = wn * 64 + nt * 16 + ml;
                bb[nt] = *(const bf16x8*)(Bs + row * 128 + (((gb ^ row) & 7) << 4));
            }
#pragma unroll
            for (int mt = 0; mt < 4; mt++)
#pragma unroll
                for (int nt = 0; nt < 4; nt++)
                    acc[mt][nt] = __builtin_amdgcn_mfma_f32_16x16x32_bf16(a[mt], bb[nt], acc[mt][nt], 0, 0, 0);
        }
        __syncthreads();
    }

    const float sc = 1.0f / 1600.0f;
    u16* ab = att + (size_t)b * 65536;
#pragma unroll
    for (int mt = 0; mt < 4; mt++)
#pragma unroll
        for (int nt = 0; nt < 4; nt++) {
            int q = q0 + wn * 64 + nt * 16 + ml;
#pragma unroll
            for (int r = 0; r < 4; r++) {
                int t = t0 + wm * 64 + mt * 16 + kq * 4 + r;
                ab[(size_t)t * 256 + q] = f2bf(tanhf(acc[mt][nt][r] * sc));
            }
        }
}

// ---------------------------------------------------------------------------
// Kernel 3b: transpose V part of qkv -> vt [b][v*64+c][q], q contiguous.
// ---------------------------------------------------------------------------
__global__ __launch_bounds__(256) void k_trv(const u16* __restrict__ qkv,
                                             u16* __restrict__ vt) {
    const int q0 = blockIdx.x * 32;
    const int c0 = blockIdx.y * 32;
    const int b  = blockIdx.z;
    const int n = b / 3, s = b % 3;
    const int tid = threadIdx.x;

    __shared__ u16 L[32 * 800];   // [c][q*25+v] for 32 q, 50 KB

    const u16* src = qkv + ((size_t)n * D3 + 384 + s * 64 + c0) * TV + q0 * 25;
#pragma unroll
    for (int r = 0; r < 13; ++r) {
        int idx = tid + 256 * r;
        if (idx < 3200) {
            int c = idx / 100, w = idx - 100 * c;
            uint4 v = *(const uint4*)(src + (size_t)c * TV + w * 8);
            *(uint4*)&L[c * 800 + w * 8] = v;
        }
    }
    __syncthreads();

    u16* dst = vt + ((size_t)b * 1600 + c0) * 256 + q0;
#pragma unroll
    for (int r = 0; r < 4; ++r) {
        int idx = tid + 256 * r;
        if (idx < 800) {
            int c = idx / 25, v = idx - 25 * c;
            const u16* lp = &L[c * 800 + v];
            u32 buf[16];
#pragma unroll
            for (int j = 0; j < 16; ++j) {
                u32 lo = lp[(2 * j) * 25];
                u32 hi = lp[(2 * j + 1) * 25];
                buf[j] = lo | (hi << 16);
            }
            u16* dp = dst + (size_t)(v * 64 + c) * 256;
#pragma unroll
            for (int q4 = 0; q4 < 4; ++q4) {
                uint4 u; u.x = buf[q4 * 4]; u.y = buf[q4 * 4 + 1];
                u.z = buf[q4 * 4 + 2]; u.w = buf[q4 * 4 + 3];
                *(uint4*)(dp + q4 * 8) = u;
            }
        }
    }
}

// ---------------------------------------------------------------------------
// Kernel 4: AV MFMA.
// y[b][t][cv=v*64+c] = sum_q att[b][t][q] * vt[b][cv][q]
// ---------------------------------------------------------------------------
__global__ __launch_bounds__(256) void k_av(const u16* __restrict__ att,
                                            const u16* __restrict__ vt,
                                            u16* __restrict__ y_t) {
    const int b = blockIdx.z, t0 = blockIdx.y * 128, v = blockIdx.x;
    const int n = b / 3, s = b % 3;
    const int tid = threadIdx.x;
    const int wid = tid >> 6, lane = tid & 63;
    const int wm = wid & 1, wn = wid >> 1;
    const int ml = lane & 15, kq = lane >> 4;

    __shared__ __align__(16) char As[128 * 128];
    __shared__ __align__(16) char Bs[64 * 128];

    f32x4 acc[4][2];
#pragma unroll
    for (int i = 0; i < 4; i++)
#pragma unroll
        for (int j = 0; j < 2; j++)
#pragma unroll
            for (int r = 0; r < 4; r++) acc[i][j][r] = 0.f;

    const u16* ab = att + (size_t)b * 65536;                     // [t][q]
    const u16* vb = vt + ((size_t)b * 1600 + v * 64) * 256;      // [c][q]

    for (int kc = 0; kc < 256; kc += 64) {
#pragma unroll
        for (int r = 0; r < 4; r++) {
            int idx = tid + 256 * r;
            int row = idx >> 3, g = idx & 7;
            uint4 u = *(const uint4*)(ab + (size_t)(t0 + row) * 256 + kc + g * 8);
            *(uint4*)(As + row * 128 + (((g ^ row) & 7) << 4)) = u;
        }
#pragma unroll
        for (int r = 0; r < 2; r++) {
            int idx = tid + 256 * r;
            int row = idx >> 3, g = idx & 7;
            uint4 u = *(const uint4*)(vb + (size_t)row * 256 + kc + g * 8);
            *(uint4*)(Bs + row * 128 + (((g ^ row) & 7) << 4)) = u;
        }
        __syncthreads();
#pragma unroll
        for (int ks = 0; ks < 2; ks++) {
            int gb = ks * 4 + kq;
            bf16x8 a[4], bb[2];
#pragma unroll
            for (int mt = 0; mt < 4; mt++) {
                int row = wm * 64 + mt * 16 + ml;
                a[mt] = *(const bf16x8*)(As + row * 128 + (((gb ^ row) & 7) << 4));
            }
#pragma unroll
            for (int nt = 0; nt < 2; nt++) {
                int row = wn * 32 + nt * 16 + ml;
                bb[nt] = *(const bf16x8*)(Bs + row * 128 + (((gb ^ row) & 7) << 4));
            }
#pragma unroll
            for (int mt = 0; mt < 4; mt++)
#pragma unroll
                for (int nt = 0; nt < 2; nt++)
                    acc[mt][nt] = __builtin_amdgcn_mfma_f32_16x16x32_bf16(a[mt], bb[nt], acc[mt][nt], 0, 0, 0);
        }
        __syncthreads();
    }

#pragma unroll
    for (int mt = 0; mt < 4; mt++)
#pragma unroll
        for (int nt = 0; nt < 2; nt++) {
            int cg = s * 64 + wn * 32 + nt * 16 + ml;
#pragma unroll
            for (int r = 0; r < 4; r++) {
                int t = t0 + wm * 64 + mt * 16 + kq * 4 + r;
                y_t[((size_t)n * TV + t * 25 + v) * 192 + cg] = f2bf(acc[mt][nt][r]);
            }
        }
}

// ---------------------------------------------------------------------------
// Kernel 5: FF MFMA + BN + residual + LeakyReLU.
// Full-K restructure: By (y_t tile, 128p x 192c, 48 KB) staged ONCE;
// the 3 d-tiles loop inside (Aw restaged per tile).  y_t read 1x (was 3x),
// 6 barriers (was 18).  LDS 72 KB -> 2 blocks/CU.
// ---------------------------------------------------------------------------
__global__ __launch_bounds__(256) void k_ff(const u16* __restrict__ y_t,
                                            const float* __restrict__ x,
                                            const u16* __restrict__ w_ffb,
                                            const float* __restrict__ b_ff,
                                            const float* __restrict__ gamma,
                                            const float* __restrict__ beta,
                                            const float* __restrict__ mean,
                                            const float* __restrict__ var,
                                            float* __restrict__ out) {
    const int n = blockIdx.y, p0 = blockIdx.x * 128;
    const int tid = threadIdx.x;
    const int wid = tid >> 6, lane = tid & 63;
    const int wn = wid;
    const int ml = lane & 15, kq = lane >> 4;

    __shared__ __align__(16) char Aw[64 * 384];
    __shared__ __align__(16) char By[128 * 384];

    // Stage By once: 128 rows x 192 c (3072 uint4)
#pragma unroll
    for (int r = 0; r < 12; ++r) {
        int idx = tid + 256 * r;
        int row = idx / 24, g = idx - row * 24;
        uint4 v = *(const uint4*)(y_t + ((size_t)n * TV + p0 + row) * 192 + g * 8);
        *(uint4*)(By + row * 384 + (((g & ~7) | ((g ^ row) & 7)) << 4)) = v;
    }

    for (int dt = 0; dt < 3; ++dt) {
        // Stage Aw: w_ff rows dt*64..+64, all 192 c (1536 uint4)
#pragma unroll
        for (int r = 0; r < 6; ++r) {
            int idx = tid + 256 * r;
            int row = idx / 24, g = idx - row * 24;
            uint4 v = *(const uint4*)(w_ffb + (size_t)(dt * 64 + row) * 192 + g * 8);
            *(uint4*)(Aw + row * 384 + (((g & ~7) | ((g ^ row) & 7)) << 4)) = v;
        }
        __syncthreads();

        f32x4 acc[4][2];
#pragma unroll
        for (int i = 0; i < 4; i++)
#pragma unroll
            for (int j = 0; j < 2; j++)
#pragma unroll
                for (int r = 0; r < 4; r++) acc[i][j][r] = 0.f;

#pragma unroll
        for (int kk = 0; kk < 3; ++kk)
#pragma unroll
            for (int ks = 0; ks < 2; ++ks) {
                int g = kk * 8 + ks * 4 + kq;
                bf16x8 a[4], bb[2];
#pragma unroll
                for (int mt = 0; mt < 4; mt++) {
                    int row = mt * 16 + ml;
                    a[mt] = *(const bf16x8*)(Aw + row * 384 + (((g & ~7) | ((g ^ row) & 7)) << 4));
                }
#pragma unroll
                for (int nt = 0; nt < 2; nt++) {
                    int row = wn * 32 + nt * 16 + ml;
                    bb[nt] = *(const bf16x8*)(By + row * 384 + (((g & ~7) | ((g ^ row) & 7)) << 4));
                }
#pragma unroll
                for (int mt = 0; mt < 4; mt++)
#pragma unroll
                    for (int nt = 0; nt < 2; nt++)
                        acc[mt][nt] = __builtin_amdgcn_mfma_f32_16x16x32_bf16(a[mt], bb[nt], acc[mt][nt], 0, 0, 0);
            }

#pragma unroll
        for (int mt = 0; mt < 4; mt++)
#pragma unroll
            for (int r = 0; r < 4; r++) {
                int d = dt * 64 + mt * 16 + kq * 4 + r;
                float inv = gamma[d] * rsqrtf(var[d] + 1e-5f);
                float bias = b_ff[d], mu = mean[d], bt = beta[d];
#pragma unroll
                for (int nt = 0; nt < 2; nt++) {
                    int p = p0 + wn * 32 + nt * 16 + ml;
                    size_t xi = ((size_t)n * NCH + d) * TV + p;
                    float v = acc[mt][nt][r] + bias;
                    v = (v - mu) * inv + bt;
                    float z = x[xi] + v;
                    out[xi] = (z >= 0.f) ? z : 0.1f * z;
                }
            }
        __syncthreads();
    }
}

// ---------------------------------------------------------------------------
extern "C" void kernel_launch(void* const* d_in, const int* in_sizes, int n_in,
                              void* d_out, int out_size, void* d_ws, size_t ws_size,
                              hipStream_t stream) {
    const float* x     = (const float*)d_in[0];
    const float* w_in  = (const float*)d_in[1];
    const float* b_in  = (const float*)d_in[2];
    const float* w_ff  = (const float*)d_in[3];
    const float* b_ff  = (const float*)d_in[4];
    const float* gamma = (const float*)d_in[5];
    const float* beta  = (const float*)d_in[6];
    const float* mean  = (const float*)d_in[7];
    const float* var   = (const float*)d_in[8];

    // ws: qkv bf16 (only V region d in [384,576) used) [0,235929600) |
    // att bf16 [..,248512512) | y_t bf16 [..,327155712) | w_bf [..,327450624)
    u16* qkv = (u16*)d_ws;
    u16* att = (u16*)((char*)d_ws + 235929600ull);
    u16* y_t = (u16*)((char*)d_ws + 248512512ull);
    u32* wb  = (u32*)((char*)d_ws + 327155712ull);
    u16* w_inb = (u16*)wb;
    u16* w_ffb = w_inb + 110592;
    // d_out scratch: qt/kt written directly by k_qkv (transposed layout);
    // after k_scores consumes them, vt aliases qt; k_ff overwrites all last.
    u16* qt = (u16*)d_out;
    u16* kt = qt + 39321600ull;
    u16* vt = qt;
    float* out = (float*)d_out;

    k_wcast <<<dim3(288),        dim3(256), 0, stream>>>(w_in, w_ff, wb);
    k_qkv   <<<dim3(100, 32),    dim3(256), 0, stream>>>(x, w_inb, b_in, qkv, qt, kt);
    k_scores<<<dim3(2, 2, 96),   dim3(256), 0, stream>>>(qt, kt, att);
    k_trv   <<<dim3(8, 2, 96),   dim3(256), 0, stream>>>(qkv, vt);
    k_av    <<<dim3(25, 2, 96),  dim3(256), 0, stream>>>(att, vt, y_t);
    k_ff    <<<dim3(50, 32),     dim3(256), 0, stream>>>(y_t, x, w_ffb, b_ff, gamma, beta, mean, var, out);
}